// Round 16
// baseline (3515.778 us; speedup 1.0000x reference)
//
#include <hip/hip_runtime.h>
#include <math.h>

#define NL 4096      // 2*N_VARS literals
#define NV 2048      // N_VARS
#define NC 8192      // N_CLAUSES
#define DIM 128
#define NG 512       // 4*DIM LSTM gates
#define NROUNDS 26

#define CSEG 64
#define CSEGLEN 64
#define CSEGCAP 8
#define LSEG 32
#define LSEGLEN 256
#define LSEGCAP 16
#define CCAP 32
#define LCAP 48

__device__ __forceinline__ float sigf(float x){ return 1.0f/(1.0f+expf(-x)); }

// ---- generic tiled transpose: dst[C][R] = src[R][C]^T ----------------------
__global__ void k_transpose(const float* __restrict__ src, float* __restrict__ dst,
                            int R, int C){
  __shared__ float t[32][33];
  int cb = blockIdx.x*32, rb = blockIdx.y*32;
  int x = threadIdx.x, y = threadIdx.y;
  for (int i = y; i < 32; i += 8){
    int r = rb+i, c = cb+x;
    if (r < R && c < C) t[i][x] = src[(size_t)r*C + c];
  }
  __syncthreads();
  for (int i = y; i < 32; i += 8){
    int c = cb+i, r = rb+x;
    if (c < C && r < R) dst[(size_t)c*R + r] = t[x][i];
  }
}

// gate-quad permute: dst[koff+k][4d+g] = W[g*128+d][k]
__global__ void k_permq(const float* __restrict__ W, int K,
                        float* __restrict__ dst, int koff){
  int idx = blockIdx.x*blockDim.x + threadIdx.x;
  if (idx >= K*NG) return;
  int k = idx >> 9, j = idx & (NG-1);
  int g = j & 3, d = j >> 2;
  dst[(size_t)(koff+k)*NG + j] = W[(size_t)(g*DIM+d)*K + k];
}

__global__ void k_permb(const float* __restrict__ bih, const float* __restrict__ bhh,
                        float* __restrict__ bq){
  int j = blockIdx.x*blockDim.x + threadIdx.x;
  if (j >= NG) return;
  int g = j & 3, d = j >> 2;
  bq[j] = bih[g*DIM+d] + bhh[g*DIM+d];
}

// ---- adjacency build (float4-vectorized scans) -----------------------------
__global__ void k_build_cseg(const float* __restrict__ adj,
                             int* __restrict__ scnt, int* __restrict__ slst){
  int idx = blockIdx.x*blockDim.x + threadIdx.x;   // [0, (NC/4)*CSEG)
  int c4 = idx & (NC/4 - 1);
  int s  = idx >> 11;
  if (s >= CSEG) return;
  int base = s*CSEGLEN;
  int c0 = c4*4;
  int n0=0, n1=0, n2=0, n3=0;
  for (int i = 0; i < CSEGLEN; ++i){
    float4 v = *(const float4*)&adj[(size_t)(base+i)*NC + c0];
    if (v.x != 0.f){ if (n0 < CSEGCAP) slst[((size_t)(c0+0)*CSEG + s)*CSEGCAP + n0] = base+i; ++n0; }
    if (v.y != 0.f){ if (n1 < CSEGCAP) slst[((size_t)(c0+1)*CSEG + s)*CSEGCAP + n1] = base+i; ++n1; }
    if (v.z != 0.f){ if (n2 < CSEGCAP) slst[((size_t)(c0+2)*CSEG + s)*CSEGCAP + n2] = base+i; ++n2; }
    if (v.w != 0.f){ if (n3 < CSEGCAP) slst[((size_t)(c0+3)*CSEG + s)*CSEGCAP + n3] = base+i; ++n3; }
  }
  scnt[(c0+0)*CSEG + s] = n0 < CSEGCAP ? n0 : CSEGCAP;
  scnt[(c0+1)*CSEG + s] = n1 < CSEGCAP ? n1 : CSEGCAP;
  scnt[(c0+2)*CSEG + s] = n2 < CSEGCAP ? n2 : CSEGCAP;
  scnt[(c0+3)*CSEG + s] = n3 < CSEGCAP ? n3 : CSEGCAP;
}

__global__ void k_build_lseg(const float* __restrict__ adj,
                             int* __restrict__ scnt, int* __restrict__ slst){
  int gtid = blockIdx.x*blockDim.x + threadIdx.x;
  int wid  = gtid >> 6;
  int lane = threadIdx.x & 63;
  int l = wid >> 5;
  int s = wid & (LSEG-1);
  if (l >= NL) return;
  int base = s*LSEGLEN;
  int c0 = base + lane*4;
  float4 v = *(const float4*)&adj[(size_t)l*NC + c0];
  float vv[4] = {v.x, v.y, v.z, v.w};
  unsigned long long below = (lane == 0) ? 0ull : ((1ull<<lane)-1ull);
  int* out = slst + ((size_t)l*LSEG + s)*LSEGCAP;
  unsigned long long m[4];
  int nb = 0;
#pragma unroll
  for (int j = 0; j < 4; ++j){
    m[j] = __ballot(vv[j] != 0.f);
    nb += __popcll(m[j] & below);
  }
  int myoff = 0;
#pragma unroll
  for (int j = 0; j < 4; ++j){
    if (vv[j] != 0.f){
      int pos = nb + myoff;
      if (pos < LSEGCAP) out[pos] = c0 + j;
      ++myoff;
    }
  }
  if (lane == 0){
    int tot = 0;
#pragma unroll
    for (int j = 0; j < 4; ++j) tot += __popcll(m[j]);
    scnt[l*LSEG+s] = tot < LSEGCAP ? tot : LSEGCAP;
  }
}

__global__ void k_merge_c(const int* __restrict__ scnt, const int* __restrict__ slst,
                          int* __restrict__ cnt, int* __restrict__ lst){
  int c = blockIdx.x*blockDim.x + threadIdx.x;
  if (c >= NC) return;
  int n = 0;
  for (int s = 0; s < CSEG; ++s){
    int m = scnt[c*CSEG+s];
    const int* in = slst + ((size_t)c*CSEG+s)*CSEGCAP;
    for (int t = 0; t < m; ++t){ if (n < CCAP) lst[(size_t)c*CCAP+n] = in[t]; ++n; }
  }
  cnt[c] = n < CCAP ? n : CCAP;
}

__global__ void k_merge_l(const int* __restrict__ scnt, const int* __restrict__ slst,
                          int* __restrict__ cnt, int* __restrict__ lst){
  int l = blockIdx.x*blockDim.x + threadIdx.x;
  if (l >= NL) return;
  int n = 0;
  for (int s = 0; s < LSEG; ++s){
    int m = scnt[l*LSEG+s];
    const int* in = slst + ((size_t)l*LSEG+s)*LSEGCAP;
    for (int t = 0; t < m; ++t){ if (n < LCAP) lst[(size_t)l*LCAP+n] = in[t]; ++n; }
  }
  cnt[l] = n < LCAP ? n : LCAP;
}

// ---- state init ------------------------------------------------------------
__global__ void k_init(const float* __restrict__ liw, const float* __restrict__ lib,
                       const float* __restrict__ ciw, const float* __restrict__ cib,
                       float* __restrict__ Lh, float* __restrict__ Lc,
                       float* __restrict__ Ch, float* __restrict__ Cc){
  int idx = blockIdx.x*blockDim.x + threadIdx.x;
  int d = idx & (DIM-1);
  if (idx < NL*DIM){ Lh[idx] = liw[d] + lib[d]; Lc[idx] = 0.0f; }
  if (idx < NC*DIM){ Ch[idx] = ciw[d] + cib[d]; Cc[idx] = 0.0f; }
}

// ---- sparse gather: out[r][:] = sum_{e in list(r)} X[e][:] -----------------
template<int CAP>
__global__ __launch_bounds__(256)
void k_gather(const float* __restrict__ X,
              const int* __restrict__ cnt, const int* __restrict__ lst,
              float* __restrict__ out){
  int tid = threadIdx.x;
  int r = blockIdx.x*8 + (tid>>5);
  int q = tid & 31;
  float4 s = make_float4(0.f,0.f,0.f,0.f);
  int n = cnt[r];
  const int* ls = lst + (size_t)r*CAP;
  for (int e = 0; e < n; ++e){
    float4 u = *(const float4*)&X[(size_t)ls[e]*DIM + q*4];
    s.x += u.x; s.y += u.y; s.z += u.z; s.w += u.w;
  }
  *(float4*)&out[(size_t)r*DIM + q*4] = s;
}

// ============================================================================
// LDS-tiled dense LSTM GEMM + pointwise epilogue.
// Load-ahead pipelined + DOUBLE-BUFFERED LDS: one barrier per k-tile.
// 256 thr, BM=64, BN=64, BK=16, TM=4, TN=4. Same math/k-order as round 15.
// ASRC: 1 = clause (K=256: [msg|h]), 2 = literal (K=384: [msg|flip|h]).
// ============================================================================
template<int ASRC>
__global__ __launch_bounds__(256)
void k_lstm(const float* __restrict__ Xmsg,
            const float* __restrict__ Hin,
            const float* __restrict__ Wq, const float* __restrict__ bq,
            float* __restrict__ Cst, float* __restrict__ Hout){
  constexpr int KT = (ASRC==1) ? 256 : 384;
  constexpr int NT = KT/16;
  __shared__ __align__(16) float As[2][16][68];
  __shared__ __align__(16) float4 Bs4[2][256];
  int tid = threadIdx.x;
  int tx = tid & 15, ty = tid >> 4;
  int m0 = blockIdx.x*64, n0 = blockIdx.y*64;
  int arow = tid >> 2, akq = tid & 3;
  int grow = m0 + arow;
  int frow = (grow + NV) & (NL-1);
  int bk = tid >> 4, bc = tid & 15;

  float acc[4][4];
#pragma unroll
  for (int r = 0; r < 4; ++r)
#pragma unroll
    for (int c = 0; c < 4; ++c) acc[r][c] = 0.f;

  float4 av, av2, bv, bv2;
  auto LOADT = [&](int t, float4& a_out, float4& b_out){
    int k0 = t*16;
    const float* ap;
    if (ASRC == 1){
      ap = (k0 < 128) ? &Xmsg[(size_t)grow*DIM + k0]
                      : &Hin[(size_t)grow*DIM + (k0-128)];
    } else {
      ap = (k0 < 128) ? &Xmsg[(size_t)grow*DIM + k0]
         : (k0 < 256) ? &Hin[(size_t)frow*DIM + (k0-128)]
                      : &Hin[(size_t)grow*DIM + (k0-256)];
    }
    a_out = *(const float4*)(ap + akq*4);
    b_out = *(const float4*)&Wq[(size_t)(k0+bk)*NG + n0 + bc*4];
  };
  auto WRITE = [&](int buf, const float4& a_in, const float4& b_in){
    As[buf][akq*4+0][arow] = a_in.x;
    As[buf][akq*4+1][arow] = a_in.y;
    As[buf][akq*4+2][arow] = a_in.z;
    As[buf][akq*4+3][arow] = a_in.w;
    Bs4[buf][bk*16 + bc] = b_in;
  };

  LOADT(0, av, bv);
  WRITE(0, av, bv);
  __syncthreads();
  for (int t = 0; t < NT; ++t){
    int cur = t & 1;
    if (t+1 < NT) LOADT(t+1, av2, bv2);   // issue next loads first
#pragma unroll
    for (int k = 0; k < 16; ++k){
      float4 a = *(const float4*)&As[cur][k][ty*4];
      float ar[4] = {a.x, a.y, a.z, a.w};
      float4 b0 = Bs4[cur][k*16 + tx];
      float br[4] = {b0.x, b0.y, b0.z, b0.w};
#pragma unroll
      for (int r = 0; r < 4; ++r)
#pragma unroll
        for (int c = 0; c < 4; ++c) acc[r][c] += ar[r]*br[c];
    }
    if (t+1 < NT) WRITE(1-cur, av2, bv2); // other buffer: no race with readers
    __syncthreads();                      // single barrier per tile
  }

  // LSTM pointwise epilogue (quad-permuted gate cols: n = 4d+g)
  float4 bqv = *(const float4*)&bq[n0 + tx*4];
  int d = (n0 >> 2) + tx;
#pragma unroll
  for (int rr = 0; rr < 4; ++rr){
    int row = m0 + ty*4 + rr;
    float c = Cst[(size_t)row*DIM + d];
    float ig = acc[rr][0]+bqv.x, fg = acc[rr][1]+bqv.y;
    float gg = acc[rr][2]+bqv.z, og = acc[rr][3]+bqv.w;
    float cn = sigf(fg)*c + sigf(ig)*tanhf(gg);
    float hn = sigf(og)*tanhf(cn);
    Cst[(size_t)row*DIM + d]  = cn;
    Hout[(size_t)row*DIM + d] = hn;
  }
}

// ============================================================================
// Fused 3-layer MLP: 256 thr, BM=8 rows/block, TM=1, TN=4.
// Load-ahead + double-buffered weight staging: one barrier per k-tile.
// Same math/k-order as round 15.
// ============================================================================
template<int BM>
__global__ __launch_bounds__(256)
void k_mlp3r(const float* __restrict__ in, float* __restrict__ out,
             const float* __restrict__ w1, const float* __restrict__ b1,
             const float* __restrict__ w2, const float* __restrict__ b2,
             const float* __restrict__ w3, const float* __restrict__ b3){
  constexpr int TM = BM/8;
  __shared__ __align__(16) float xs[BM][132];
  __shared__ __align__(16) float4 Bs4[2][512];
  int tid = threadIdx.x;
  int tx = tid & 31, ty = tid >> 5;     // tx: col quad, ty: row group
  int m0 = blockIdx.x*BM;
  int s0k = tid >> 5, s0c = tid & 31;
  int s1k = (tid+256) >> 5, s1c = tid & 31;
#pragma unroll
  for (int i = 0; i < BM/8; ++i){
    int idx = tid + i*256;
    int row = idx >> 5, c4 = idx & 31;
    *(float4*)&xs[row][c4*4] = *(const float4*)&in[(size_t)(m0+row)*DIM + c4*4];
  }
  const float* W[3] = {w1, w2, w3};
  const float* B[3] = {b1, b2, b3};
#pragma unroll
  for (int l = 0; l < 3; ++l){
    float acc[TM][4];
#pragma unroll
    for (int r = 0; r < TM; ++r)
#pragma unroll
      for (int c = 0; c < 4; ++c) acc[r][c] = 0.f;
    float4 wv0 = *(const float4*)&W[l][(size_t)s0k*DIM + s0c*4];
    float4 wv1 = *(const float4*)&W[l][(size_t)s1k*DIM + s1c*4];
    Bs4[0][s0k*32 + s0c] = wv0;
    Bs4[0][s1k*32 + s1c] = wv1;
    __syncthreads();                    // covers xs writes + Bs[0] stage
    for (int kt = 0; kt < 8; ++kt){
      int cur = kt & 1;
      if (kt+1 < 8){
        wv0 = *(const float4*)&W[l][(size_t)((kt+1)*16+s0k)*DIM + s0c*4];
        wv1 = *(const float4*)&W[l][(size_t)((kt+1)*16+s1k)*DIM + s1c*4];
      }
#pragma unroll
      for (int k4 = 0; k4 < 4; ++k4){
        float4 a[TM];
#pragma unroll
        for (int r = 0; r < TM; ++r)
          a[r] = *(const float4*)&xs[ty*TM+r][kt*16 + k4*4];
#pragma unroll
        for (int kk = 0; kk < 4; ++kk){
          float4 b = Bs4[cur][(k4*4+kk)*32 + tx];
          float br[4] = {b.x, b.y, b.z, b.w};
#pragma unroll
          for (int r = 0; r < TM; ++r){
            float av = (kk==0) ? a[r].x : (kk==1) ? a[r].y : (kk==2) ? a[r].z : a[r].w;
#pragma unroll
            for (int c = 0; c < 4; ++c) acc[r][c] += av*br[c];
          }
        }
      }
      if (kt+1 < 8){
        Bs4[1-cur][s0k*32 + s0c] = wv0;
        Bs4[1-cur][s1k*32 + s1c] = wv1;
      }
      __syncthreads();                  // single barrier per tile
    }
    float4 bb = *(const float4*)&B[l][tx*4];
    if (l < 2){
      // all xs reads of this layer completed before the final barrier above
#pragma unroll
      for (int r = 0; r < TM; ++r){
        float4 v = make_float4(fmaxf(acc[r][0]+bb.x, 0.f), fmaxf(acc[r][1]+bb.y, 0.f),
                               fmaxf(acc[r][2]+bb.z, 0.f), fmaxf(acc[r][3]+bb.w, 0.f));
        *(float4*)&xs[ty*TM+r][tx*4] = v;
      }
    } else {
#pragma unroll
      for (int r = 0; r < TM; ++r){
        int row = m0 + ty*TM + r;
        float4 v = make_float4(acc[r][0]+bb.x, acc[r][1]+bb.y,
                               acc[r][2]+bb.z, acc[r][3]+bb.w);
        *(float4*)&out[(size_t)row*DIM + tx*4] = v;
      }
    }
  }
}

// ---- vote MLP + logits copy ------------------------------------------------
template<bool RELU>
__device__ __forceinline__ void mlp_layer8v(const float (*__restrict__ xs)[DIM],
                                            float (*__restrict__ ys)[DIM],
                                            const float* __restrict__ Wt,
                                            const float* __restrict__ B, int tid){
  int j4 = (tid & 31)*4, slot = tid >> 5;
  float a0=0.f, a1=0.f, a2=0.f, a3=0.f;
#pragma unroll 4
  for (int k = 0; k < DIM; k += 4){
    float4 w0 = *(const float4*)&Wt[(size_t)(k+0)*DIM + j4];
    float4 w1 = *(const float4*)&Wt[(size_t)(k+1)*DIM + j4];
    float4 w2 = *(const float4*)&Wt[(size_t)(k+2)*DIM + j4];
    float4 w3 = *(const float4*)&Wt[(size_t)(k+3)*DIM + j4];
    float4 x  = *(const float4*)&xs[slot][k];
    a0 += x.x*w0.x + x.y*w1.x + x.z*w2.x + x.w*w3.x;
    a1 += x.x*w0.y + x.y*w1.y + x.z*w2.y + x.w*w3.y;
    a2 += x.x*w0.z + x.y*w1.z + x.z*w2.z + x.w*w3.z;
    a3 += x.x*w0.w + x.y*w1.w + x.z*w2.w + x.w*w3.w;
  }
  float4 b = *(const float4*)&B[j4];
  float4 v = make_float4(a0+b.x, a1+b.y, a2+b.z, a3+b.w);
  if (RELU){
    v.x = fmaxf(v.x,0.f); v.y = fmaxf(v.y,0.f);
    v.z = fmaxf(v.z,0.f); v.w = fmaxf(v.w,0.f);
  }
  *(float4*)&ys[slot][j4] = v;
}

__global__ __launch_bounds__(256, 4)
void k_vote(const float* __restrict__ Lh, float* __restrict__ vote,
            float* __restrict__ dout,
            const float* __restrict__ w1t, const float* __restrict__ b1,
            const float* __restrict__ w2t, const float* __restrict__ b2,
            const float* __restrict__ w3, const float* __restrict__ b3){
  __shared__ __align__(16) float xs[8][DIM];
  __shared__ __align__(16) float ys[8][DIM];
  int r0 = blockIdx.x*8;
  int tid = threadIdx.x;
  {
    int row = tid >> 5, c4 = (tid & 31)*4;
    float4 v = *(const float4*)&Lh[(size_t)(r0+row)*DIM + c4];
    *(float4*)&xs[row][c4] = v;
    *(float4*)&dout[1 + NL + (size_t)(r0+row)*DIM + c4] = v;   // logits out
  }
  __syncthreads();
  mlp_layer8v<true>(xs, ys, w1t, b1, tid);
  __syncthreads();
  mlp_layer8v<true>(ys, xs, w2t, b2, tid);
  __syncthreads();
  int r = tid >> 5, lane32 = tid & 31;
  float4 x = *(const float4*)&xs[r][lane32*4];
  float4 w = *(const float4*)&w3[lane32*4];
  float pp = x.x*w.x + x.y*w.y + x.z*w.z + x.w*w.w;
  pp += __shfl_down(pp, 16, 32);
  pp += __shfl_down(pp, 8, 32);
  pp += __shfl_down(pp, 4, 32);
  pp += __shfl_down(pp, 2, 32);
  pp += __shfl_down(pp, 1, 32);
  if (lane32 == 0){
    float t = pp + b3[0];
    vote[r0+r] = t;
    dout[1 + r0 + r] = t;
  }
}

__global__ void k_mean(const float* __restrict__ vote, float* __restrict__ dout){
  __shared__ float red[256];
  int tid = threadIdx.x;
  float s = 0.f;
  for (int i = tid; i < NL; i += 256) s += vote[i];
  red[tid] = s;
  __syncthreads();
  for (int w = 128; w > 0; w >>= 1){
    if (tid < w) red[tid] += red[tid+w];
    __syncthreads();
  }
  if (tid == 0) dout[0] = red[0] / (float)NL;
}

// ---- host ------------------------------------------------------------------
static inline void launch_transpose(const float* src, float* dst, int R, int C,
                                    hipStream_t stream){
  dim3 g((C+31)/32, (R+31)/32), b(32, 8);
  k_transpose<<<g, b, 0, stream>>>(src, dst, R, C);
}

extern "C" void kernel_launch(void* const* d_in, const int* in_sizes, int n_in,
                              void* d_out, int out_size, void* d_ws, size_t ws_size,
                              hipStream_t stream){
  const float* adj      = (const float*)d_in[0];
  const float* l_init_w = (const float*)d_in[1];
  const float* l_init_b = (const float*)d_in[2];
  const float* c_init_w = (const float*)d_in[3];
  const float* c_init_b = (const float*)d_in[4];
  const float* lmsg_w1  = (const float*)d_in[5];
  const float* lmsg_b1  = (const float*)d_in[6];
  const float* lmsg_w2  = (const float*)d_in[7];
  const float* lmsg_b2  = (const float*)d_in[8];
  const float* lmsg_w3  = (const float*)d_in[9];
  const float* lmsg_b3  = (const float*)d_in[10];
  const float* cmsg_w1  = (const float*)d_in[11];
  const float* cmsg_b1  = (const float*)d_in[12];
  const float* cmsg_w2  = (const float*)d_in[13];
  const float* cmsg_b2  = (const float*)d_in[14];
  const float* cmsg_w3  = (const float*)d_in[15];
  const float* cmsg_b3  = (const float*)d_in[16];
  const float* l_wih    = (const float*)d_in[17];
  const float* l_whh    = (const float*)d_in[18];
  const float* l_bih    = (const float*)d_in[19];
  const float* l_bhh    = (const float*)d_in[20];
  const float* c_wih    = (const float*)d_in[21];
  const float* c_whh    = (const float*)d_in[22];
  const float* c_bih    = (const float*)d_in[23];
  const float* c_bhh    = (const float*)d_in[24];
  const float* lvote_w1 = (const float*)d_in[25];
  const float* lvote_b1 = (const float*)d_in[26];
  const float* lvote_w2 = (const float*)d_in[27];
  const float* lvote_b2 = (const float*)d_in[28];
  const float* lvote_w3 = (const float*)d_in[29];
  const float* lvote_b3 = (const float*)d_in[30];

  char* p = (char*)d_ws;
  auto alloc = [&](size_t bytes) -> void* {
    void* r = (void*)p;
    p += (bytes + 255) & ~(size_t)255;
    return r;
  };
  // persistent
  float* LhA   = (float*)alloc((size_t)NL*DIM*4);
  float* LhB   = (float*)alloc((size_t)NL*DIM*4);
  float* Lc    = (float*)alloc((size_t)NL*DIM*4);
  float* ChA   = (float*)alloc((size_t)NC*DIM*4);
  float* Cc    = (float*)alloc((size_t)NC*DIM*4);
  float* vote  = (float*)alloc((size_t)NL*4);
  int* ccnt    = (int*)alloc((size_t)NC*4);
  int* clst    = (int*)alloc((size_t)NC*CCAP*4);
  int* lcnt    = (int*)alloc((size_t)NL*4);
  int* llst    = (int*)alloc((size_t)NL*LCAP*4);
  float* lm1t  = (float*)alloc((size_t)DIM*DIM*4);
  float* lm2t  = (float*)alloc((size_t)DIM*DIM*4);
  float* lm3t  = (float*)alloc((size_t)DIM*DIM*4);
  float* cm1t  = (float*)alloc((size_t)DIM*DIM*4);
  float* cm2t  = (float*)alloc((size_t)DIM*DIM*4);
  float* cm3t  = (float*)alloc((size_t)DIM*DIM*4);
  float* vw1t  = (float*)alloc((size_t)DIM*DIM*4);
  float* vw2t  = (float*)alloc((size_t)DIM*DIM*4);
  float* WqC   = (float*)alloc((size_t)256*NG*4);
  float* WqL   = (float*)alloc((size_t)384*NG*4);
  float* bqC   = (float*)alloc((size_t)NG*4);
  float* bqL   = (float*)alloc((size_t)NG*4);
  // scratch union: build-phase seg buffers alias round-phase buffers
  char* scratch = (char*)alloc((size_t)28*1024*1024);
  int* scnt_c  = (int*)scratch;
  int* slst_c  = (int*)(scratch + (size_t)NC*CSEG*4);
  int* scnt_l  = (int*)(scratch + (size_t)(NC*CSEG + NC*CSEG*CSEGCAP)*4);
  int* slst_l  = (int*)(scratch + (size_t)(NC*CSEG + NC*CSEG*CSEGCAP + NL*LSEG)*4);
  float* ChB   = (float*)(scratch);                                 // 4 MB
  float* Cpre  = (float*)(scratch + (size_t)4*1024*1024);           // 4 MB
  float* Lpre  = (float*)(scratch + (size_t)8*1024*1024);           // 2 MB
  float* Cmsg  = (float*)(scratch + (size_t)10*1024*1024);          // 4 MB
  float* Lmsg  = (float*)(scratch + (size_t)14*1024*1024);          // 2 MB
  (void)ws_size; (void)in_sizes; (void)n_in; (void)out_size;

  // weight prep
  launch_transpose(lmsg_w1, lm1t, DIM, DIM, stream);
  launch_transpose(lmsg_w2, lm2t, DIM, DIM, stream);
  launch_transpose(lmsg_w3, lm3t, DIM, DIM, stream);
  launch_transpose(cmsg_w1, cm1t, DIM, DIM, stream);
  launch_transpose(cmsg_w2, cm2t, DIM, DIM, stream);
  launch_transpose(cmsg_w3, cm3t, DIM, DIM, stream);
  launch_transpose(lvote_w1, vw1t, DIM, DIM, stream);
  launch_transpose(lvote_w2, vw2t, DIM, DIM, stream);
  k_permq<<<(128*NG)/256, 256, 0, stream>>>(c_wih, 128, WqC, 0);
  k_permq<<<(128*NG)/256, 256, 0, stream>>>(c_whh, 128, WqC, 128);
  k_permq<<<(256*NG)/256, 256, 0, stream>>>(l_wih, 256, WqL, 0);
  k_permq<<<(128*NG)/256, 256, 0, stream>>>(l_whh, 128, WqL, 256);
  k_permb<<<NG/256, 256, 0, stream>>>(c_bih, c_bhh, bqC);
  k_permb<<<NG/256, 256, 0, stream>>>(l_bih, l_bhh, bqL);

  // adjacency build (vectorized), then merge to persistent compact lists
  k_build_cseg<<<(NC/4)*CSEG/256, 256, 0, stream>>>(adj, scnt_c, slst_c);
  k_build_lseg<<<NL*LSEG*64/256, 256, 0, stream>>>(adj, scnt_l, slst_l);
  k_merge_c<<<NC/256, 256, 0, stream>>>(scnt_c, slst_c, ccnt, clst);
  k_merge_l<<<NL/256, 256, 0, stream>>>(scnt_l, slst_l, lcnt, llst);
  k_init<<<NC*DIM/256, 256, 0, stream>>>(l_init_w, l_init_b, c_init_w, c_init_b,
                                         LhA, Lc, ChA, Cc);

  float* Lh_cur = LhA; float* Lh_nxt = LhB;
  float* Ch_cur = ChA; float* Ch_nxt = ChB;

  // prologue: Lpre for round 0
  k_mlp3r<8><<<NL/8, 256, 0, stream>>>(Lh_cur, Lpre,
                                       lm1t, lmsg_b1, lm2t, lmsg_b2, lm3t, lmsg_b3);
  for (int r = 0; r < NROUNDS; ++r){
    k_gather<CCAP><<<NC/8, 256, 0, stream>>>(Lpre, ccnt, clst, Cmsg);
    k_lstm<1><<<dim3(NC/64, 8), 256, 0, stream>>>(Cmsg, Ch_cur, WqC, bqC, Cc, Ch_nxt);
    k_mlp3r<8><<<NC/8, 256, 0, stream>>>(Ch_nxt, Cpre,
                                         cm1t, cmsg_b1, cm2t, cmsg_b2, cm3t, cmsg_b3);
    k_gather<LCAP><<<NL/8, 256, 0, stream>>>(Cpre, lcnt, llst, Lmsg);
    k_lstm<2><<<dim3(NL/64, 8), 256, 0, stream>>>(Lmsg, Lh_cur, WqL, bqL, Lc, Lh_nxt);
    k_mlp3r<8><<<NL/8, 256, 0, stream>>>(Lh_nxt, Lpre,
                                         lm1t, lmsg_b1, lm2t, lmsg_b2, lm3t, lmsg_b3);
    float* t;
    t = Lh_cur; Lh_cur = Lh_nxt; Lh_nxt = t;
    t = Ch_cur; Ch_cur = Ch_nxt; Ch_nxt = t;
  }

  k_vote<<<NL/8, 256, 0, stream>>>(Lh_cur, vote, (float*)d_out,
                                   vw1t, lvote_b1, vw2t, lvote_b2,
                                   lvote_w3, lvote_b3);
  k_mean<<<1, 256, 0, stream>>>(vote, (float*)d_out);
}

// Round 17
// 3251.167 us; speedup vs baseline: 1.0814x; 1.0814x over previous
//
#include <hip/hip_runtime.h>
#include <math.h>

#define NL 4096      // 2*N_VARS literals
#define NV 2048      // N_VARS
#define NC 8192      // N_CLAUSES
#define DIM 128
#define NG 512       // 4*DIM LSTM gates
#define NROUNDS 26

#define CSEG 64
#define CSEGLEN 64
#define CSEGCAP 8
#define LSEG 32
#define LSEGLEN 256
#define LSEGCAP 16
#define CCAP 32
#define LCAP 48

__device__ __forceinline__ float sigf(float x){ return 1.0f/(1.0f+expf(-x)); }

// ---- generic tiled transpose: dst[C][R] = src[R][C]^T ----------------------
__global__ void k_transpose(const float* __restrict__ src, float* __restrict__ dst,
                            int R, int C){
  __shared__ float t[32][33];
  int cb = blockIdx.x*32, rb = blockIdx.y*32;
  int x = threadIdx.x, y = threadIdx.y;
  for (int i = y; i < 32; i += 8){
    int r = rb+i, c = cb+x;
    if (r < R && c < C) t[i][x] = src[(size_t)r*C + c];
  }
  __syncthreads();
  for (int i = y; i < 32; i += 8){
    int c = cb+i, r = rb+x;
    if (c < C && r < R) dst[(size_t)c*R + r] = t[x][i];
  }
}

// gate-quad permute: dst[koff+k][4d+g] = W[g*128+d][k]
__global__ void k_permq(const float* __restrict__ W, int K,
                        float* __restrict__ dst, int koff){
  int idx = blockIdx.x*blockDim.x + threadIdx.x;
  if (idx >= K*NG) return;
  int k = idx >> 9, j = idx & (NG-1);
  int g = j & 3, d = j >> 2;
  dst[(size_t)(koff+k)*NG + j] = W[(size_t)(g*DIM+d)*K + k];
}

__global__ void k_permb(const float* __restrict__ bih, const float* __restrict__ bhh,
                        float* __restrict__ bq){
  int j = blockIdx.x*blockDim.x + threadIdx.x;
  if (j >= NG) return;
  int g = j & 3, d = j >> 2;
  bq[j] = bih[g*DIM+d] + bhh[g*DIM+d];
}

// ---- adjacency build (float4-vectorized scans) -----------------------------
__global__ void k_build_cseg(const float* __restrict__ adj,
                             int* __restrict__ scnt, int* __restrict__ slst){
  int idx = blockIdx.x*blockDim.x + threadIdx.x;   // [0, (NC/4)*CSEG)
  int c4 = idx & (NC/4 - 1);
  int s  = idx >> 11;
  if (s >= CSEG) return;
  int base = s*CSEGLEN;
  int c0 = c4*4;
  int n0=0, n1=0, n2=0, n3=0;
  for (int i = 0; i < CSEGLEN; ++i){
    float4 v = *(const float4*)&adj[(size_t)(base+i)*NC + c0];
    if (v.x != 0.f){ if (n0 < CSEGCAP) slst[((size_t)(c0+0)*CSEG + s)*CSEGCAP + n0] = base+i; ++n0; }
    if (v.y != 0.f){ if (n1 < CSEGCAP) slst[((size_t)(c0+1)*CSEG + s)*CSEGCAP + n1] = base+i; ++n1; }
    if (v.z != 0.f){ if (n2 < CSEGCAP) slst[((size_t)(c0+2)*CSEG + s)*CSEGCAP + n2] = base+i; ++n2; }
    if (v.w != 0.f){ if (n3 < CSEGCAP) slst[((size_t)(c0+3)*CSEG + s)*CSEGCAP + n3] = base+i; ++n3; }
  }
  scnt[(c0+0)*CSEG + s] = n0 < CSEGCAP ? n0 : CSEGCAP;
  scnt[(c0+1)*CSEG + s] = n1 < CSEGCAP ? n1 : CSEGCAP;
  scnt[(c0+2)*CSEG + s] = n2 < CSEGCAP ? n2 : CSEGCAP;
  scnt[(c0+3)*CSEG + s] = n3 < CSEGCAP ? n3 : CSEGCAP;
}

__global__ void k_build_lseg(const float* __restrict__ adj,
                             int* __restrict__ scnt, int* __restrict__ slst){
  int gtid = blockIdx.x*blockDim.x + threadIdx.x;
  int wid  = gtid >> 6;
  int lane = threadIdx.x & 63;
  int l = wid >> 5;
  int s = wid & (LSEG-1);
  if (l >= NL) return;
  int base = s*LSEGLEN;
  int c0 = base + lane*4;
  float4 v = *(const float4*)&adj[(size_t)l*NC + c0];
  float vv[4] = {v.x, v.y, v.z, v.w};
  unsigned long long below = (lane == 0) ? 0ull : ((1ull<<lane)-1ull);
  int* out = slst + ((size_t)l*LSEG + s)*LSEGCAP;
  unsigned long long m[4];
  int nb = 0;
#pragma unroll
  for (int j = 0; j < 4; ++j){
    m[j] = __ballot(vv[j] != 0.f);
    nb += __popcll(m[j] & below);
  }
  int myoff = 0;
#pragma unroll
  for (int j = 0; j < 4; ++j){
    if (vv[j] != 0.f){
      int pos = nb + myoff;
      if (pos < LSEGCAP) out[pos] = c0 + j;
      ++myoff;
    }
  }
  if (lane == 0){
    int tot = 0;
#pragma unroll
    for (int j = 0; j < 4; ++j) tot += __popcll(m[j]);
    scnt[l*LSEG+s] = tot < LSEGCAP ? tot : LSEGCAP;
  }
}

__global__ void k_merge_c(const int* __restrict__ scnt, const int* __restrict__ slst,
                          int* __restrict__ cnt, int* __restrict__ lst){
  int c = blockIdx.x*blockDim.x + threadIdx.x;
  if (c >= NC) return;
  int n = 0;
  for (int s = 0; s < CSEG; ++s){
    int m = scnt[c*CSEG+s];
    const int* in = slst + ((size_t)c*CSEG+s)*CSEGCAP;
    for (int t = 0; t < m; ++t){ if (n < CCAP) lst[(size_t)c*CCAP+n] = in[t]; ++n; }
  }
  cnt[c] = n < CCAP ? n : CCAP;
}

__global__ void k_merge_l(const int* __restrict__ scnt, const int* __restrict__ slst,
                          int* __restrict__ cnt, int* __restrict__ lst){
  int l = blockIdx.x*blockDim.x + threadIdx.x;
  if (l >= NL) return;
  int n = 0;
  for (int s = 0; s < LSEG; ++s){
    int m = scnt[l*LSEG+s];
    const int* in = slst + ((size_t)l*LSEG+s)*LSEGCAP;
    for (int t = 0; t < m; ++t){ if (n < LCAP) lst[(size_t)l*LCAP+n] = in[t]; ++n; }
  }
  cnt[l] = n < LCAP ? n : LCAP;
}

// ---- state init ------------------------------------------------------------
__global__ void k_init(const float* __restrict__ liw, const float* __restrict__ lib,
                       const float* __restrict__ ciw, const float* __restrict__ cib,
                       float* __restrict__ Lh, float* __restrict__ Lc,
                       float* __restrict__ Ch, float* __restrict__ Cc){
  int idx = blockIdx.x*blockDim.x + threadIdx.x;
  int d = idx & (DIM-1);
  if (idx < NL*DIM){ Lh[idx] = liw[d] + lib[d]; Lc[idx] = 0.0f; }
  if (idx < NC*DIM){ Ch[idx] = ciw[d] + cib[d]; Cc[idx] = 0.0f; }
}

// ---- sparse gather (software-pipelined list walk; sequential sum order) ----
template<int CAP>
__global__ __launch_bounds__(256)
void k_gather(const float* __restrict__ X,
              const int* __restrict__ cnt, const int* __restrict__ lst,
              float* __restrict__ out){
  int tid = threadIdx.x;
  int r = blockIdx.x*8 + (tid>>5);
  int q = tid & 31;
  float4 s = make_float4(0.f,0.f,0.f,0.f);
  int n = cnt[r];
  const int* ls = lst + (size_t)r*CAP;
  if (n > 0){
    float4 u = *(const float4*)&X[(size_t)ls[0]*DIM + q*4];
    for (int e = 1; e < n; ++e){
      float4 un = *(const float4*)&X[(size_t)ls[e]*DIM + q*4];  // prefetch e
      s.x += u.x; s.y += u.y; s.z += u.z; s.w += u.w;           // add e-1
      u = un;
    }
    s.x += u.x; s.y += u.y; s.z += u.z; s.w += u.w;
  }
  *(float4*)&out[(size_t)r*DIM + q*4] = s;
}

// ============================================================================
// LDS-tiled dense LSTM GEMM + pointwise epilogue, load-ahead pipelined.
// 256 thr, BM=64, BK=16, TM=4; BN=64 (TN=4). (Round-15 verified winner.)
// ASRC: 1 = clause (K=256: [msg|h]), 2 = literal (K=384: [msg|flip|h]).
// ============================================================================
template<int ASRC, int BN>
__global__ __launch_bounds__(256)
void k_lstm(const float* __restrict__ Xmsg,
            const float* __restrict__ Hin,
            const float* __restrict__ Wq, const float* __restrict__ bq,
            float* __restrict__ Cst, float* __restrict__ Hout){
  constexpr int KT  = (ASRC==1) ? 256 : 384;
  constexpr int NT  = KT/16;
  constexpr int TN  = BN/16;          // 4
  constexpr int BQ  = BN/4;           // 16
  constexpr int NBS = (16*BQ)/256;    // 1
  __shared__ __align__(16) float As[16][68];
  __shared__ __align__(16) float4 Bs4[16*BQ];
  int tid = threadIdx.x;
  int tx = tid & 15, ty = tid >> 4;
  int m0 = blockIdx.x*64, n0 = blockIdx.y*BN;
  int arow = tid >> 2, akq = tid & 3;
  int grow = m0 + arow;
  int frow = (grow + NV) & (NL-1);

  float acc[4][TN];
#pragma unroll
  for (int r = 0; r < 4; ++r)
#pragma unroll
    for (int c = 0; c < TN; ++c) acc[r][c] = 0.f;

  float4 av, av2;
  float4 bv[NBS], bv2[NBS];

  auto LOADT = [&](int t, float4& a_out, float4* b_out){
    int k0 = t*16;
    const float* ap;
    if (ASRC == 1){
      ap = (k0 < 128) ? &Xmsg[(size_t)grow*DIM + k0]
                      : &Hin[(size_t)grow*DIM + (k0-128)];
    } else {
      ap = (k0 < 128) ? &Xmsg[(size_t)grow*DIM + k0]
         : (k0 < 256) ? &Hin[(size_t)frow*DIM + (k0-128)]
                      : &Hin[(size_t)grow*DIM + (k0-256)];
    }
    a_out = *(const float4*)(ap + akq*4);
#pragma unroll
    for (int i = 0; i < NBS; ++i){
      int s = tid + i*256;
      int bk = s / BQ, bc = s % BQ;
      b_out[i] = *(const float4*)&Wq[(size_t)(k0+bk)*NG + n0 + bc*4];
    }
  };

  LOADT(0, av, bv);
  for (int t = 0; t < NT; ++t){
    __syncthreads();                     // previous tile's compute done
    As[akq*4+0][arow] = av.x;
    As[akq*4+1][arow] = av.y;
    As[akq*4+2][arow] = av.z;
    As[akq*4+3][arow] = av.w;
#pragma unroll
    for (int i = 0; i < NBS; ++i){
      int s = tid + i*256;
      int bk = s / BQ, bc = s % BQ;
      Bs4[bk*16 + bc] = bv[i];
    }
    __syncthreads();
    if (t+1 < NT) LOADT(t+1, av2, bv2);  // issue next loads BEFORE compute
#pragma unroll
    for (int k = 0; k < 16; ++k){
      float4 a = *(const float4*)&As[k][ty*4];
      float ar[4] = {a.x, a.y, a.z, a.w};
      float4 b0 = Bs4[k*16 + tx];
      float br[4] = {b0.x, b0.y, b0.z, b0.w};
#pragma unroll
      for (int r = 0; r < 4; ++r)
#pragma unroll
        for (int c = 0; c < 4; ++c) acc[r][c] += ar[r]*br[c];
    }
    av = av2;
#pragma unroll
    for (int i = 0; i < NBS; ++i) bv[i] = bv2[i];
  }

  // LSTM pointwise epilogue (quad-permuted gate cols: n = 4d+g)
  float4 bqv = *(const float4*)&bq[n0 + tx*4];
  int d = (n0 >> 2) + tx;
#pragma unroll
  for (int rr = 0; rr < 4; ++rr){
    int row = m0 + ty*4 + rr;
    float c = Cst[(size_t)row*DIM + d];
    float ig = acc[rr][0]+bqv.x, fg = acc[rr][1]+bqv.y;
    float gg = acc[rr][2]+bqv.z, og = acc[rr][3]+bqv.w;
    float cn = sigf(fg)*c + sigf(ig)*tanhf(gg);
    float hn = sigf(og)*tanhf(cn);
    Cst[(size_t)row*DIM + d]  = cn;
    Hout[(size_t)row*DIM + d] = hn;
  }
}

// ============================================================================
// Fused 3-layer MLP: 256 thr, BM=8 rows/block, TM=1, TN=4, load-ahead
// pipelined weight staging. (Round-15 verified winner.)
// ============================================================================
template<int BM>
__global__ __launch_bounds__(256)
void k_mlp3r(const float* __restrict__ in, float* __restrict__ out,
             const float* __restrict__ w1, const float* __restrict__ b1,
             const float* __restrict__ w2, const float* __restrict__ b2,
             const float* __restrict__ w3, const float* __restrict__ b3){
  constexpr int TM = BM/8;
  __shared__ __align__(16) float xs[BM][132];
  __shared__ __align__(16) float4 Bs4[512];
  int tid = threadIdx.x;
  int tx = tid & 31, ty = tid >> 5;     // tx: col quad, ty: row group
  int m0 = blockIdx.x*BM;
  int s0k = tid >> 5, s0c = tid & 31;
  int s1k = (tid+256) >> 5, s1c = tid & 31;
#pragma unroll
  for (int i = 0; i < BM/8; ++i){
    int idx = tid + i*256;
    int row = idx >> 5, c4 = idx & 31;
    *(float4*)&xs[row][c4*4] = *(const float4*)&in[(size_t)(m0+row)*DIM + c4*4];
  }
  const float* W[3] = {w1, w2, w3};
  const float* B[3] = {b1, b2, b3};
#pragma unroll
  for (int l = 0; l < 3; ++l){
    float acc[TM][4];
#pragma unroll
    for (int r = 0; r < TM; ++r)
#pragma unroll
      for (int c = 0; c < 4; ++c) acc[r][c] = 0.f;
    float4 wv0 = *(const float4*)&W[l][(size_t)s0k*DIM + s0c*4];
    float4 wv1 = *(const float4*)&W[l][(size_t)s1k*DIM + s1c*4];
    for (int kt = 0; kt < 8; ++kt){
      __syncthreads();                  // previous compute done / xs ready
      Bs4[s0k*32 + s0c] = wv0;
      Bs4[s1k*32 + s1c] = wv1;
      __syncthreads();
      if (kt+1 < 8){
        wv0 = *(const float4*)&W[l][(size_t)((kt+1)*16+s0k)*DIM + s0c*4];
        wv1 = *(const float4*)&W[l][(size_t)((kt+1)*16+s1k)*DIM + s1c*4];
      }
#pragma unroll
      for (int k4 = 0; k4 < 4; ++k4){
        float4 a[TM];
#pragma unroll
        for (int r = 0; r < TM; ++r)
          a[r] = *(const float4*)&xs[ty*TM+r][kt*16 + k4*4];
#pragma unroll
        for (int kk = 0; kk < 4; ++kk){
          float4 b = Bs4[(k4*4+kk)*32 + tx];
          float br[4] = {b.x, b.y, b.z, b.w};
#pragma unroll
          for (int r = 0; r < TM; ++r){
            float av = (kk==0) ? a[r].x : (kk==1) ? a[r].y : (kk==2) ? a[r].z : a[r].w;
#pragma unroll
            for (int c = 0; c < 4; ++c) acc[r][c] += av*br[c];
          }
        }
      }
    }
    float4 bb = *(const float4*)&B[l][tx*4];
    if (l < 2){
      __syncthreads();                  // all reads of xs done
#pragma unroll
      for (int r = 0; r < TM; ++r){
        float4 v = make_float4(fmaxf(acc[r][0]+bb.x, 0.f), fmaxf(acc[r][1]+bb.y, 0.f),
                               fmaxf(acc[r][2]+bb.z, 0.f), fmaxf(acc[r][3]+bb.w, 0.f));
        *(float4*)&xs[ty*TM+r][tx*4] = v;
      }
    } else {
#pragma unroll
      for (int r = 0; r < TM; ++r){
        int row = m0 + ty*TM + r;
        float4 v = make_float4(acc[r][0]+bb.x, acc[r][1]+bb.y,
                               acc[r][2]+bb.z, acc[r][3]+bb.w);
        *(float4*)&out[(size_t)row*DIM + tx*4] = v;
      }
    }
  }
}

// ---- vote MLP + logits copy ------------------------------------------------
template<bool RELU>
__device__ __forceinline__ void mlp_layer8v(const float (*__restrict__ xs)[DIM],
                                            float (*__restrict__ ys)[DIM],
                                            const float* __restrict__ Wt,
                                            const float* __restrict__ B, int tid){
  int j4 = (tid & 31)*4, slot = tid >> 5;
  float a0=0.f, a1=0.f, a2=0.f, a3=0.f;
#pragma unroll 4
  for (int k = 0; k < DIM; k += 4){
    float4 w0 = *(const float4*)&Wt[(size_t)(k+0)*DIM + j4];
    float4 w1 = *(const float4*)&Wt[(size_t)(k+1)*DIM + j4];
    float4 w2 = *(const float4*)&Wt[(size_t)(k+2)*DIM + j4];
    float4 w3 = *(const float4*)&Wt[(size_t)(k+3)*DIM + j4];
    float4 x  = *(const float4*)&xs[slot][k];
    a0 += x.x*w0.x + x.y*w1.x + x.z*w2.x + x.w*w3.x;
    a1 += x.x*w0.y + x.y*w1.y + x.z*w2.y + x.w*w3.y;
    a2 += x.x*w0.z + x.y*w1.z + x.z*w2.z + x.w*w3.z;
    a3 += x.x*w0.w + x.y*w1.w + x.z*w2.w + x.w*w3.w;
  }
  float4 b = *(const float4*)&B[j4];
  float4 v = make_float4(a0+b.x, a1+b.y, a2+b.z, a3+b.w);
  if (RELU){
    v.x = fmaxf(v.x,0.f); v.y = fmaxf(v.y,0.f);
    v.z = fmaxf(v.z,0.f); v.w = fmaxf(v.w,0.f);
  }
  *(float4*)&ys[slot][j4] = v;
}

__global__ __launch_bounds__(256, 4)
void k_vote(const float* __restrict__ Lh, float* __restrict__ vote,
            float* __restrict__ dout,
            const float* __restrict__ w1t, const float* __restrict__ b1,
            const float* __restrict__ w2t, const float* __restrict__ b2,
            const float* __restrict__ w3, const float* __restrict__ b3){
  __shared__ __align__(16) float xs[8][DIM];
  __shared__ __align__(16) float ys[8][DIM];
  int r0 = blockIdx.x*8;
  int tid = threadIdx.x;
  {
    int row = tid >> 5, c4 = (tid & 31)*4;
    float4 v = *(const float4*)&Lh[(size_t)(r0+row)*DIM + c4];
    *(float4*)&xs[row][c4] = v;
    *(float4*)&dout[1 + NL + (size_t)(r0+row)*DIM + c4] = v;   // logits out
  }
  __syncthreads();
  mlp_layer8v<true>(xs, ys, w1t, b1, tid);
  __syncthreads();
  mlp_layer8v<true>(ys, xs, w2t, b2, tid);
  __syncthreads();
  int r = tid >> 5, lane32 = tid & 31;
  float4 x = *(const float4*)&xs[r][lane32*4];
  float4 w = *(const float4*)&w3[lane32*4];
  float pp = x.x*w.x + x.y*w.y + x.z*w.z + x.w*w.w;
  pp += __shfl_down(pp, 16, 32);
  pp += __shfl_down(pp, 8, 32);
  pp += __shfl_down(pp, 4, 32);
  pp += __shfl_down(pp, 2, 32);
  pp += __shfl_down(pp, 1, 32);
  if (lane32 == 0){
    float t = pp + b3[0];
    vote[r0+r] = t;
    dout[1 + r0 + r] = t;
  }
}

__global__ void k_mean(const float* __restrict__ vote, float* __restrict__ dout){
  __shared__ float red[256];
  int tid = threadIdx.x;
  float s = 0.f;
  for (int i = tid; i < NL; i += 256) s += vote[i];
  red[tid] = s;
  __syncthreads();
  for (int w = 128; w > 0; w >>= 1){
    if (tid < w) red[tid] += red[tid+w];
    __syncthreads();
  }
  if (tid == 0) dout[0] = red[0] / (float)NL;
}

// ---- host ------------------------------------------------------------------
static inline void launch_transpose(const float* src, float* dst, int R, int C,
                                    hipStream_t stream){
  dim3 g((C+31)/32, (R+31)/32), b(32, 8);
  k_transpose<<<g, b, 0, stream>>>(src, dst, R, C);
}

extern "C" void kernel_launch(void* const* d_in, const int* in_sizes, int n_in,
                              void* d_out, int out_size, void* d_ws, size_t ws_size,
                              hipStream_t stream){
  const float* adj      = (const float*)d_in[0];
  const float* l_init_w = (const float*)d_in[1];
  const float* l_init_b = (const float*)d_in[2];
  const float* c_init_w = (const float*)d_in[3];
  const float* c_init_b = (const float*)d_in[4];
  const float* lmsg_w1  = (const float*)d_in[5];
  const float* lmsg_b1  = (const float*)d_in[6];
  const float* lmsg_w2  = (const float*)d_in[7];
  const float* lmsg_b2  = (const float*)d_in[8];
  const float* lmsg_w3  = (const float*)d_in[9];
  const float* lmsg_b3  = (const float*)d_in[10];
  const float* cmsg_w1  = (const float*)d_in[11];
  const float* cmsg_b1  = (const float*)d_in[12];
  const float* cmsg_w2  = (const float*)d_in[13];
  const float* cmsg_b2  = (const float*)d_in[14];
  const float* cmsg_w3  = (const float*)d_in[15];
  const float* cmsg_b3  = (const float*)d_in[16];
  const float* l_wih    = (const float*)d_in[17];
  const float* l_whh    = (const float*)d_in[18];
  const float* l_bih    = (const float*)d_in[19];
  const float* l_bhh    = (const float*)d_in[20];
  const float* c_wih    = (const float*)d_in[21];
  const float* c_whh    = (const float*)d_in[22];
  const float* c_bih    = (const float*)d_in[23];
  const float* c_bhh    = (const float*)d_in[24];
  const float* lvote_w1 = (const float*)d_in[25];
  const float* lvote_b1 = (const float*)d_in[26];
  const float* lvote_w2 = (const float*)d_in[27];
  const float* lvote_b2 = (const float*)d_in[28];
  const float* lvote_w3 = (const float*)d_in[29];
  const float* lvote_b3 = (const float*)d_in[30];

  char* p = (char*)d_ws;
  auto alloc = [&](size_t bytes) -> void* {
    void* r = (void*)p;
    p += (bytes + 255) & ~(size_t)255;
    return r;
  };
  // persistent
  float* LhA   = (float*)alloc((size_t)NL*DIM*4);
  float* LhB   = (float*)alloc((size_t)NL*DIM*4);
  float* Lc    = (float*)alloc((size_t)NL*DIM*4);
  float* ChA   = (float*)alloc((size_t)NC*DIM*4);
  float* Cc    = (float*)alloc((size_t)NC*DIM*4);
  float* vote  = (float*)alloc((size_t)NL*4);
  int* ccnt    = (int*)alloc((size_t)NC*4);
  int* clst    = (int*)alloc((size_t)NC*CCAP*4);
  int* lcnt    = (int*)alloc((size_t)NL*4);
  int* llst    = (int*)alloc((size_t)NL*LCAP*4);
  float* lm1t  = (float*)alloc((size_t)DIM*DIM*4);
  float* lm2t  = (float*)alloc((size_t)DIM*DIM*4);
  float* lm3t  = (float*)alloc((size_t)DIM*DIM*4);
  float* cm1t  = (float*)alloc((size_t)DIM*DIM*4);
  float* cm2t  = (float*)alloc((size_t)DIM*DIM*4);
  float* cm3t  = (float*)alloc((size_t)DIM*DIM*4);
  float* vw1t  = (float*)alloc((size_t)DIM*DIM*4);
  float* vw2t  = (float*)alloc((size_t)DIM*DIM*4);
  float* WqC   = (float*)alloc((size_t)256*NG*4);
  float* WqL   = (float*)alloc((size_t)384*NG*4);
  float* bqC   = (float*)alloc((size_t)NG*4);
  float* bqL   = (float*)alloc((size_t)NG*4);
  // scratch union: build-phase seg buffers alias round-phase buffers
  char* scratch = (char*)alloc((size_t)28*1024*1024);
  int* scnt_c  = (int*)scratch;
  int* slst_c  = (int*)(scratch + (size_t)NC*CSEG*4);
  int* scnt_l  = (int*)(scratch + (size_t)(NC*CSEG + NC*CSEG*CSEGCAP)*4);
  int* slst_l  = (int*)(scratch + (size_t)(NC*CSEG + NC*CSEG*CSEGCAP + NL*LSEG)*4);
  float* ChB   = (float*)(scratch);                                 // 4 MB
  float* Cpre  = (float*)(scratch + (size_t)4*1024*1024);           // 4 MB
  float* Lpre  = (float*)(scratch + (size_t)8*1024*1024);           // 2 MB
  float* Cmsg  = (float*)(scratch + (size_t)10*1024*1024);          // 4 MB
  float* Lmsg  = (float*)(scratch + (size_t)14*1024*1024);          // 2 MB
  (void)ws_size; (void)in_sizes; (void)n_in; (void)out_size;

  // weight prep
  launch_transpose(lmsg_w1, lm1t, DIM, DIM, stream);
  launch_transpose(lmsg_w2, lm2t, DIM, DIM, stream);
  launch_transpose(lmsg_w3, lm3t, DIM, DIM, stream);
  launch_transpose(cmsg_w1, cm1t, DIM, DIM, stream);
  launch_transpose(cmsg_w2, cm2t, DIM, DIM, stream);
  launch_transpose(cmsg_w3, cm3t, DIM, DIM, stream);
  launch_transpose(lvote_w1, vw1t, DIM, DIM, stream);
  launch_transpose(lvote_w2, vw2t, DIM, DIM, stream);
  k_permq<<<(128*NG)/256, 256, 0, stream>>>(c_wih, 128, WqC, 0);
  k_permq<<<(128*NG)/256, 256, 0, stream>>>(c_whh, 128, WqC, 128);
  k_permq<<<(256*NG)/256, 256, 0, stream>>>(l_wih, 256, WqL, 0);
  k_permq<<<(128*NG)/256, 256, 0, stream>>>(l_whh, 128, WqL, 256);
  k_permb<<<NG/256, 256, 0, stream>>>(c_bih, c_bhh, bqC);
  k_permb<<<NG/256, 256, 0, stream>>>(l_bih, l_bhh, bqL);

  // adjacency build (vectorized), then merge to persistent compact lists
  k_build_cseg<<<(NC/4)*CSEG/256, 256, 0, stream>>>(adj, scnt_c, slst_c);
  k_build_lseg<<<NL*LSEG*64/256, 256, 0, stream>>>(adj, scnt_l, slst_l);
  k_merge_c<<<NC/256, 256, 0, stream>>>(scnt_c, slst_c, ccnt, clst);
  k_merge_l<<<NL/256, 256, 0, stream>>>(scnt_l, slst_l, lcnt, llst);
  k_init<<<NC*DIM/256, 256, 0, stream>>>(l_init_w, l_init_b, c_init_w, c_init_b,
                                         LhA, Lc, ChA, Cc);

  float* Lh_cur = LhA; float* Lh_nxt = LhB;
  float* Ch_cur = ChA; float* Ch_nxt = ChB;

  // prologue: Lpre for round 0
  k_mlp3r<8><<<NL/8, 256, 0, stream>>>(Lh_cur, Lpre,
                                       lm1t, lmsg_b1, lm2t, lmsg_b2, lm3t, lmsg_b3);
  for (int r = 0; r < NROUNDS; ++r){
    k_gather<CCAP><<<NC/8, 256, 0, stream>>>(Lpre, ccnt, clst, Cmsg);
    k_lstm<1,64><<<dim3(NC/64, 8), 256, 0, stream>>>(Cmsg, Ch_cur, WqC, bqC, Cc, Ch_nxt);
    k_mlp3r<8><<<NC/8, 256, 0, stream>>>(Ch_nxt, Cpre,
                                         cm1t, cmsg_b1, cm2t, cmsg_b2, cm3t, cmsg_b3);
    k_gather<LCAP><<<NL/8, 256, 0, stream>>>(Cpre, lcnt, llst, Lmsg);
    k_lstm<2,64><<<dim3(NL/64, 8), 256, 0, stream>>>(Lmsg, Lh_cur, WqL, bqL, Lc, Lh_nxt);
    k_mlp3r<8><<<NL/8, 256, 0, stream>>>(Lh_nxt, Lpre,
                                         lm1t, lmsg_b1, lm2t, lmsg_b2, lm3t, lmsg_b3);
    float* t;
    t = Lh_cur; Lh_cur = Lh_nxt; Lh_nxt = t;
    t = Ch_cur; Ch_cur = Ch_nxt; Ch_nxt = t;
  }

  k_vote<<<NL/8, 256, 0, stream>>>(Lh_cur, vote, (float*)d_out,
                                   vw1t, lvote_b1, vw2t, lvote_b2,
                                   lvote_w3, lvote_b3);
  k_mean<<<1, 256, 0, stream>>>(vote, (float*)d_out);
}

// Round 18
// 3188.748 us; speedup vs baseline: 1.1026x; 1.0196x over previous
//
#include <hip/hip_runtime.h>
#include <math.h>

#define NL 4096      // 2*N_VARS literals
#define NV 2048      // N_VARS
#define NC 8192      // N_CLAUSES
#define DIM 128
#define NG 512       // 4*DIM LSTM gates
#define NROUNDS 26

#define CSEG 64
#define CSEGLEN 64
#define CSEGCAP 8
#define LSEG 32
#define LSEGLEN 256
#define LSEGCAP 16
#define CCAP 32
#define LCAP 48

__device__ __forceinline__ float sigf(float x){ return 1.0f/(1.0f+expf(-x)); }

// ---- generic tiled transpose: dst[C][R] = src[R][C]^T ----------------------
__global__ void k_transpose(const float* __restrict__ src, float* __restrict__ dst,
                            int R, int C){
  __shared__ float t[32][33];
  int cb = blockIdx.x*32, rb = blockIdx.y*32;
  int x = threadIdx.x, y = threadIdx.y;
  for (int i = y; i < 32; i += 8){
    int r = rb+i, c = cb+x;
    if (r < R && c < C) t[i][x] = src[(size_t)r*C + c];
  }
  __syncthreads();
  for (int i = y; i < 32; i += 8){
    int c = cb+i, r = rb+x;
    if (c < C && r < R) dst[(size_t)c*R + r] = t[x][i];
  }
}

// gate-quad permute: dst[koff+k][4d+g] = W[g*128+d][k]
__global__ void k_permq(const float* __restrict__ W, int K,
                        float* __restrict__ dst, int koff){
  int idx = blockIdx.x*blockDim.x + threadIdx.x;
  if (idx >= K*NG) return;
  int k = idx >> 9, j = idx & (NG-1);
  int g = j & 3, d = j >> 2;
  dst[(size_t)(koff+k)*NG + j] = W[(size_t)(g*DIM+d)*K + k];
}

__global__ void k_permb(const float* __restrict__ bih, const float* __restrict__ bhh,
                        float* __restrict__ bq){
  int j = blockIdx.x*blockDim.x + threadIdx.x;
  if (j >= NG) return;
  int g = j & 3, d = j >> 2;
  bq[j] = bih[g*DIM+d] + bhh[g*DIM+d];
}

// ---- adjacency build (float4-vectorized scans) -----------------------------
__global__ void k_build_cseg(const float* __restrict__ adj,
                             int* __restrict__ scnt, int* __restrict__ slst){
  int idx = blockIdx.x*blockDim.x + threadIdx.x;   // [0, (NC/4)*CSEG)
  int c4 = idx & (NC/4 - 1);
  int s  = idx >> 11;
  if (s >= CSEG) return;
  int base = s*CSEGLEN;
  int c0 = c4*4;
  int n0=0, n1=0, n2=0, n3=0;
  for (int i = 0; i < CSEGLEN; ++i){
    float4 v = *(const float4*)&adj[(size_t)(base+i)*NC + c0];
    if (v.x != 0.f){ if (n0 < CSEGCAP) slst[((size_t)(c0+0)*CSEG + s)*CSEGCAP + n0] = base+i; ++n0; }
    if (v.y != 0.f){ if (n1 < CSEGCAP) slst[((size_t)(c0+1)*CSEG + s)*CSEGCAP + n1] = base+i; ++n1; }
    if (v.z != 0.f){ if (n2 < CSEGCAP) slst[((size_t)(c0+2)*CSEG + s)*CSEGCAP + n2] = base+i; ++n2; }
    if (v.w != 0.f){ if (n3 < CSEGCAP) slst[((size_t)(c0+3)*CSEG + s)*CSEGCAP + n3] = base+i; ++n3; }
  }
  scnt[(c0+0)*CSEG + s] = n0 < CSEGCAP ? n0 : CSEGCAP;
  scnt[(c0+1)*CSEG + s] = n1 < CSEGCAP ? n1 : CSEGCAP;
  scnt[(c0+2)*CSEG + s] = n2 < CSEGCAP ? n2 : CSEGCAP;
  scnt[(c0+3)*CSEG + s] = n3 < CSEGCAP ? n3 : CSEGCAP;
}

__global__ void k_build_lseg(const float* __restrict__ adj,
                             int* __restrict__ scnt, int* __restrict__ slst){
  int gtid = blockIdx.x*blockDim.x + threadIdx.x;
  int wid  = gtid >> 6;
  int lane = threadIdx.x & 63;
  int l = wid >> 5;
  int s = wid & (LSEG-1);
  if (l >= NL) return;
  int base = s*LSEGLEN;
  int c0 = base + lane*4;
  float4 v = *(const float4*)&adj[(size_t)l*NC + c0];
  float vv[4] = {v.x, v.y, v.z, v.w};
  unsigned long long below = (lane == 0) ? 0ull : ((1ull<<lane)-1ull);
  int* out = slst + ((size_t)l*LSEG + s)*LSEGCAP;
  unsigned long long m[4];
  int nb = 0;
#pragma unroll
  for (int j = 0; j < 4; ++j){
    m[j] = __ballot(vv[j] != 0.f);
    nb += __popcll(m[j] & below);
  }
  int myoff = 0;
#pragma unroll
  for (int j = 0; j < 4; ++j){
    if (vv[j] != 0.f){
      int pos = nb + myoff;
      if (pos < LSEGCAP) out[pos] = c0 + j;
      ++myoff;
    }
  }
  if (lane == 0){
    int tot = 0;
#pragma unroll
    for (int j = 0; j < 4; ++j) tot += __popcll(m[j]);
    scnt[l*LSEG+s] = tot < LSEGCAP ? tot : LSEGCAP;
  }
}

__global__ void k_merge_c(const int* __restrict__ scnt, const int* __restrict__ slst,
                          int* __restrict__ cnt, int* __restrict__ lst){
  int c = blockIdx.x*blockDim.x + threadIdx.x;
  if (c >= NC) return;
  int n = 0;
  for (int s = 0; s < CSEG; ++s){
    int m = scnt[c*CSEG+s];
    const int* in = slst + ((size_t)c*CSEG+s)*CSEGCAP;
    for (int t = 0; t < m; ++t){ if (n < CCAP) lst[(size_t)c*CCAP+n] = in[t]; ++n; }
  }
  cnt[c] = n < CCAP ? n : CCAP;
}

__global__ void k_merge_l(const int* __restrict__ scnt, const int* __restrict__ slst,
                          int* __restrict__ cnt, int* __restrict__ lst){
  int l = blockIdx.x*blockDim.x + threadIdx.x;
  if (l >= NL) return;
  int n = 0;
  for (int s = 0; s < LSEG; ++s){
    int m = scnt[l*LSEG+s];
    const int* in = slst + ((size_t)l*LSEG+s)*LSEGCAP;
    for (int t = 0; t < m; ++t){ if (n < LCAP) lst[(size_t)l*LCAP+n] = in[t]; ++n; }
  }
  cnt[l] = n < LCAP ? n : LCAP;
}

// ---- state init ------------------------------------------------------------
__global__ void k_init(const float* __restrict__ liw, const float* __restrict__ lib,
                       const float* __restrict__ ciw, const float* __restrict__ cib,
                       float* __restrict__ Lh, float* __restrict__ Lc,
                       float* __restrict__ Ch, float* __restrict__ Cc){
  int idx = blockIdx.x*blockDim.x + threadIdx.x;
  int d = idx & (DIM-1);
  if (idx < NL*DIM){ Lh[idx] = liw[d] + lib[d]; Lc[idx] = 0.0f; }
  if (idx < NC*DIM){ Ch[idx] = ciw[d] + cib[d]; Cc[idx] = 0.0f; }
}

// ---- sparse gather: 4-wide batched loads, sequential adds (exact order) ----
template<int CAP>
__global__ __launch_bounds__(256)
void k_gather(const float* __restrict__ X,
              const int* __restrict__ cnt, const int* __restrict__ lst,
              float* __restrict__ out){
  int tid = threadIdx.x;
  int r = blockIdx.x*8 + (tid>>5);
  int q = tid & 31;
  float4 s = make_float4(0.f,0.f,0.f,0.f);
  int n = cnt[r];
  const int* ls = lst + (size_t)r*CAP;
  int e = 0;
  // groups of 4: issue 4 independent loads, then add in original order
  for (; e + 4 <= n; e += 4){
    int i0 = ls[e], i1 = ls[e+1], i2 = ls[e+2], i3 = ls[e+3];
    float4 u0 = *(const float4*)&X[(size_t)i0*DIM + q*4];
    float4 u1 = *(const float4*)&X[(size_t)i1*DIM + q*4];
    float4 u2 = *(const float4*)&X[(size_t)i2*DIM + q*4];
    float4 u3 = *(const float4*)&X[(size_t)i3*DIM + q*4];
    s.x += u0.x; s.y += u0.y; s.z += u0.z; s.w += u0.w;
    s.x += u1.x; s.y += u1.y; s.z += u1.z; s.w += u1.w;
    s.x += u2.x; s.y += u2.y; s.z += u2.z; s.w += u2.w;
    s.x += u3.x; s.y += u3.y; s.z += u3.z; s.w += u3.w;
  }
  // remainder (≤3), still batched: issue then add in order
  if (e < n){
    int n_rem = n - e;
    float4 u0, u1, u2;
    u0 = *(const float4*)&X[(size_t)ls[e]*DIM + q*4];
    if (n_rem > 1) u1 = *(const float4*)&X[(size_t)ls[e+1]*DIM + q*4];
    if (n_rem > 2) u2 = *(const float4*)&X[(size_t)ls[e+2]*DIM + q*4];
    s.x += u0.x; s.y += u0.y; s.z += u0.z; s.w += u0.w;
    if (n_rem > 1){ s.x += u1.x; s.y += u1.y; s.z += u1.z; s.w += u1.w; }
    if (n_rem > 2){ s.x += u2.x; s.y += u2.y; s.z += u2.z; s.w += u2.w; }
  }
  *(float4*)&out[(size_t)r*DIM + q*4] = s;
}

// ============================================================================
// LDS-tiled dense LSTM GEMM + pointwise epilogue, load-ahead pipelined.
// 256 thr, BM=64, BK=16, TM=4; BN=64 (TN=4). (Round-15/17 verified winner.)
// ASRC: 1 = clause (K=256: [msg|h]), 2 = literal (K=384: [msg|flip|h]).
// ============================================================================
template<int ASRC, int BN>
__global__ __launch_bounds__(256)
void k_lstm(const float* __restrict__ Xmsg,
            const float* __restrict__ Hin,
            const float* __restrict__ Wq, const float* __restrict__ bq,
            float* __restrict__ Cst, float* __restrict__ Hout){
  constexpr int KT  = (ASRC==1) ? 256 : 384;
  constexpr int NT  = KT/16;
  constexpr int TN  = BN/16;          // 4
  constexpr int BQ  = BN/4;           // 16
  constexpr int NBS = (16*BQ)/256;    // 1
  __shared__ __align__(16) float As[16][68];
  __shared__ __align__(16) float4 Bs4[16*BQ];
  int tid = threadIdx.x;
  int tx = tid & 15, ty = tid >> 4;
  int m0 = blockIdx.x*64, n0 = blockIdx.y*BN;
  int arow = tid >> 2, akq = tid & 3;
  int grow = m0 + arow;
  int frow = (grow + NV) & (NL-1);

  float acc[4][TN];
#pragma unroll
  for (int r = 0; r < 4; ++r)
#pragma unroll
    for (int c = 0; c < TN; ++c) acc[r][c] = 0.f;

  float4 av, av2;
  float4 bv[NBS], bv2[NBS];

  auto LOADT = [&](int t, float4& a_out, float4* b_out){
    int k0 = t*16;
    const float* ap;
    if (ASRC == 1){
      ap = (k0 < 128) ? &Xmsg[(size_t)grow*DIM + k0]
                      : &Hin[(size_t)grow*DIM + (k0-128)];
    } else {
      ap = (k0 < 128) ? &Xmsg[(size_t)grow*DIM + k0]
         : (k0 < 256) ? &Hin[(size_t)frow*DIM + (k0-128)]
                      : &Hin[(size_t)grow*DIM + (k0-256)];
    }
    a_out = *(const float4*)(ap + akq*4);
#pragma unroll
    for (int i = 0; i < NBS; ++i){
      int s = tid + i*256;
      int bk = s / BQ, bc = s % BQ;
      b_out[i] = *(const float4*)&Wq[(size_t)(k0+bk)*NG + n0 + bc*4];
    }
  };

  LOADT(0, av, bv);
  for (int t = 0; t < NT; ++t){
    __syncthreads();                     // previous tile's compute done
    As[akq*4+0][arow] = av.x;
    As[akq*4+1][arow] = av.y;
    As[akq*4+2][arow] = av.z;
    As[akq*4+3][arow] = av.w;
#pragma unroll
    for (int i = 0; i < NBS; ++i){
      int s = tid + i*256;
      int bk = s / BQ, bc = s % BQ;
      Bs4[bk*16 + bc] = bv[i];
    }
    __syncthreads();
    if (t+1 < NT) LOADT(t+1, av2, bv2);  // issue next loads BEFORE compute
#pragma unroll
    for (int k = 0; k < 16; ++k){
      float4 a = *(const float4*)&As[k][ty*4];
      float ar[4] = {a.x, a.y, a.z, a.w};
      float4 b0 = Bs4[k*16 + tx];
      float br[4] = {b0.x, b0.y, b0.z, b0.w};
#pragma unroll
      for (int r = 0; r < 4; ++r)
#pragma unroll
        for (int c = 0; c < 4; ++c) acc[r][c] += ar[r]*br[c];
    }
    av = av2;
#pragma unroll
    for (int i = 0; i < NBS; ++i) bv[i] = bv2[i];
  }

  // LSTM pointwise epilogue (quad-permuted gate cols: n = 4d+g)
  float4 bqv = *(const float4*)&bq[n0 + tx*4];
  int d = (n0 >> 2) + tx;
#pragma unroll
  for (int rr = 0; rr < 4; ++rr){
    int row = m0 + ty*4 + rr;
    float c = Cst[(size_t)row*DIM + d];
    float ig = acc[rr][0]+bqv.x, fg = acc[rr][1]+bqv.y;
    float gg = acc[rr][2]+bqv.z, og = acc[rr][3]+bqv.w;
    float cn = sigf(fg)*c + sigf(ig)*tanhf(gg);
    float hn = sigf(og)*tanhf(cn);
    Cst[(size_t)row*DIM + d]  = cn;
    Hout[(size_t)row*DIM + d] = hn;
  }
}

// ============================================================================
// Fused 3-layer MLP: 256 thr, BM=8 rows/block, TM=1, TN=4, load-ahead
// pipelined weight staging. (Round-15/17 verified winner.)
// ============================================================================
template<int BM>
__global__ __launch_bounds__(256)
void k_mlp3r(const float* __restrict__ in, float* __restrict__ out,
             const float* __restrict__ w1, const float* __restrict__ b1,
             const float* __restrict__ w2, const float* __restrict__ b2,
             const float* __restrict__ w3, const float* __restrict__ b3){
  constexpr int TM = BM/8;
  __shared__ __align__(16) float xs[BM][132];
  __shared__ __align__(16) float4 Bs4[512];
  int tid = threadIdx.x;
  int tx = tid & 31, ty = tid >> 5;     // tx: col quad, ty: row group
  int m0 = blockIdx.x*BM;
  int s0k = tid >> 5, s0c = tid & 31;
  int s1k = (tid+256) >> 5, s1c = tid & 31;
#pragma unroll
  for (int i = 0; i < BM/8; ++i){
    int idx = tid + i*256;
    int row = idx >> 5, c4 = idx & 31;
    *(float4*)&xs[row][c4*4] = *(const float4*)&in[(size_t)(m0+row)*DIM + c4*4];
  }
  const float* W[3] = {w1, w2, w3};
  const float* B[3] = {b1, b2, b3};
#pragma unroll
  for (int l = 0; l < 3; ++l){
    float acc[TM][4];
#pragma unroll
    for (int r = 0; r < TM; ++r)
#pragma unroll
      for (int c = 0; c < 4; ++c) acc[r][c] = 0.f;
    float4 wv0 = *(const float4*)&W[l][(size_t)s0k*DIM + s0c*4];
    float4 wv1 = *(const float4*)&W[l][(size_t)s1k*DIM + s1c*4];
    for (int kt = 0; kt < 8; ++kt){
      __syncthreads();                  // previous compute done / xs ready
      Bs4[s0k*32 + s0c] = wv0;
      Bs4[s1k*32 + s1c] = wv1;
      __syncthreads();
      if (kt+1 < 8){
        wv0 = *(const float4*)&W[l][(size_t)((kt+1)*16+s0k)*DIM + s0c*4];
        wv1 = *(const float4*)&W[l][(size_t)((kt+1)*16+s1k)*DIM + s1c*4];
      }
#pragma unroll
      for (int k4 = 0; k4 < 4; ++k4){
        float4 a[TM];
#pragma unroll
        for (int r = 0; r < TM; ++r)
          a[r] = *(const float4*)&xs[ty*TM+r][kt*16 + k4*4];
#pragma unroll
        for (int kk = 0; kk < 4; ++kk){
          float4 b = Bs4[(k4*4+kk)*32 + tx];
          float br[4] = {b.x, b.y, b.z, b.w};
#pragma unroll
          for (int r = 0; r < TM; ++r){
            float av = (kk==0) ? a[r].x : (kk==1) ? a[r].y : (kk==2) ? a[r].z : a[r].w;
#pragma unroll
            for (int c = 0; c < 4; ++c) acc[r][c] += av*br[c];
          }
        }
      }
    }
    float4 bb = *(const float4*)&B[l][tx*4];
    if (l < 2){
      __syncthreads();                  // all reads of xs done
#pragma unroll
      for (int r = 0; r < TM; ++r){
        float4 v = make_float4(fmaxf(acc[r][0]+bb.x, 0.f), fmaxf(acc[r][1]+bb.y, 0.f),
                               fmaxf(acc[r][2]+bb.z, 0.f), fmaxf(acc[r][3]+bb.w, 0.f));
        *(float4*)&xs[ty*TM+r][tx*4] = v;
      }
    } else {
#pragma unroll
      for (int r = 0; r < TM; ++r){
        int row = m0 + ty*TM + r;
        float4 v = make_float4(acc[r][0]+bb.x, acc[r][1]+bb.y,
                               acc[r][2]+bb.z, acc[r][3]+bb.w);
        *(float4*)&out[(size_t)row*DIM + tx*4] = v;
      }
    }
  }
}

// ---- vote MLP + logits copy ------------------------------------------------
template<bool RELU>
__device__ __forceinline__ void mlp_layer8v(const float (*__restrict__ xs)[DIM],
                                            float (*__restrict__ ys)[DIM],
                                            const float* __restrict__ Wt,
                                            const float* __restrict__ B, int tid){
  int j4 = (tid & 31)*4, slot = tid >> 5;
  float a0=0.f, a1=0.f, a2=0.f, a3=0.f;
#pragma unroll 4
  for (int k = 0; k < DIM; k += 4){
    float4 w0 = *(const float4*)&Wt[(size_t)(k+0)*DIM + j4];
    float4 w1 = *(const float4*)&Wt[(size_t)(k+1)*DIM + j4];
    float4 w2 = *(const float4*)&Wt[(size_t)(k+2)*DIM + j4];
    float4 w3 = *(const float4*)&Wt[(size_t)(k+3)*DIM + j4];
    float4 x  = *(const float4*)&xs[slot][k];
    a0 += x.x*w0.x + x.y*w1.x + x.z*w2.x + x.w*w3.x;
    a1 += x.x*w0.y + x.y*w1.y + x.z*w2.y + x.w*w3.y;
    a2 += x.x*w0.z + x.y*w1.z + x.z*w2.z + x.w*w3.z;
    a3 += x.x*w0.w + x.y*w1.w + x.z*w2.w + x.w*w3.w;
  }
  float4 b = *(const float4*)&B[j4];
  float4 v = make_float4(a0+b.x, a1+b.y, a2+b.z, a3+b.w);
  if (RELU){
    v.x = fmaxf(v.x,0.f); v.y = fmaxf(v.y,0.f);
    v.z = fmaxf(v.z,0.f); v.w = fmaxf(v.w,0.f);
  }
  *(float4*)&ys[slot][j4] = v;
}

__global__ __launch_bounds__(256, 4)
void k_vote(const float* __restrict__ Lh, float* __restrict__ vote,
            float* __restrict__ dout,
            const float* __restrict__ w1t, const float* __restrict__ b1,
            const float* __restrict__ w2t, const float* __restrict__ b2,
            const float* __restrict__ w3, const float* __restrict__ b3){
  __shared__ __align__(16) float xs[8][DIM];
  __shared__ __align__(16) float ys[8][DIM];
  int r0 = blockIdx.x*8;
  int tid = threadIdx.x;
  {
    int row = tid >> 5, c4 = (tid & 31)*4;
    float4 v = *(const float4*)&Lh[(size_t)(r0+row)*DIM + c4];
    *(float4*)&xs[row][c4] = v;
    *(float4*)&dout[1 + NL + (size_t)(r0+row)*DIM + c4] = v;   // logits out
  }
  __syncthreads();
  mlp_layer8v<true>(xs, ys, w1t, b1, tid);
  __syncthreads();
  mlp_layer8v<true>(ys, xs, w2t, b2, tid);
  __syncthreads();
  int r = tid >> 5, lane32 = tid & 31;
  float4 x = *(const float4*)&xs[r][lane32*4];
  float4 w = *(const float4*)&w3[lane32*4];
  float pp = x.x*w.x + x.y*w.y + x.z*w.z + x.w*w.w;
  pp += __shfl_down(pp, 16, 32);
  pp += __shfl_down(pp, 8, 32);
  pp += __shfl_down(pp, 4, 32);
  pp += __shfl_down(pp, 2, 32);
  pp += __shfl_down(pp, 1, 32);
  if (lane32 == 0){
    float t = pp + b3[0];
    vote[r0+r] = t;
    dout[1 + r0 + r] = t;
  }
}

__global__ void k_mean(const float* __restrict__ vote, float* __restrict__ dout){
  __shared__ float red[256];
  int tid = threadIdx.x;
  float s = 0.f;
  for (int i = tid; i < NL; i += 256) s += vote[i];
  red[tid] = s;
  __syncthreads();
  for (int w = 128; w > 0; w >>= 1){
    if (tid < w) red[tid] += red[tid+w];
    __syncthreads();
  }
  if (tid == 0) dout[0] = red[0] / (float)NL;
}

// ---- host ------------------------------------------------------------------
static inline void launch_transpose(const float* src, float* dst, int R, int C,
                                    hipStream_t stream){
  dim3 g((C+31)/32, (R+31)/32), b(32, 8);
  k_transpose<<<g, b, 0, stream>>>(src, dst, R, C);
}

extern "C" void kernel_launch(void* const* d_in, const int* in_sizes, int n_in,
                              void* d_out, int out_size, void* d_ws, size_t ws_size,
                              hipStream_t stream){
  const float* adj      = (const float*)d_in[0];
  const float* l_init_w = (const float*)d_in[1];
  const float* l_init_b = (const float*)d_in[2];
  const float* c_init_w = (const float*)d_in[3];
  const float* c_init_b = (const float*)d_in[4];
  const float* lmsg_w1  = (const float*)d_in[5];
  const float* lmsg_b1  = (const float*)d_in[6];
  const float* lmsg_w2  = (const float*)d_in[7];
  const float* lmsg_b2  = (const float*)d_in[8];
  const float* lmsg_w3  = (const float*)d_in[9];
  const float* lmsg_b3  = (const float*)d_in[10];
  const float* cmsg_w1  = (const float*)d_in[11];
  const float* cmsg_b1  = (const float*)d_in[12];
  const float* cmsg_w2  = (const float*)d_in[13];
  const float* cmsg_b2  = (const float*)d_in[14];
  const float* cmsg_w3  = (const float*)d_in[15];
  const float* cmsg_b3  = (const float*)d_in[16];
  const float* l_wih    = (const float*)d_in[17];
  const float* l_whh    = (const float*)d_in[18];
  const float* l_bih    = (const float*)d_in[19];
  const float* l_bhh    = (const float*)d_in[20];
  const float* c_wih    = (const float*)d_in[21];
  const float* c_whh    = (const float*)d_in[22];
  const float* c_bih    = (const float*)d_in[23];
  const float* c_bhh    = (const float*)d_in[24];
  const float* lvote_w1 = (const float*)d_in[25];
  const float* lvote_b1 = (const float*)d_in[26];
  const float* lvote_w2 = (const float*)d_in[27];
  const float* lvote_b2 = (const float*)d_in[28];
  const float* lvote_w3 = (const float*)d_in[29];
  const float* lvote_b3 = (const float*)d_in[30];

  char* p = (char*)d_ws;
  auto alloc = [&](size_t bytes) -> void* {
    void* r = (void*)p;
    p += (bytes + 255) & ~(size_t)255;
    return r;
  };
  // persistent
  float* LhA   = (float*)alloc((size_t)NL*DIM*4);
  float* LhB   = (float*)alloc((size_t)NL*DIM*4);
  float* Lc    = (float*)alloc((size_t)NL*DIM*4);
  float* ChA   = (float*)alloc((size_t)NC*DIM*4);
  float* Cc    = (float*)alloc((size_t)NC*DIM*4);
  float* vote  = (float*)alloc((size_t)NL*4);
  int* ccnt    = (int*)alloc((size_t)NC*4);
  int* clst    = (int*)alloc((size_t)NC*CCAP*4);
  int* lcnt    = (int*)alloc((size_t)NL*4);
  int* llst    = (int*)alloc((size_t)NL*LCAP*4);
  float* lm1t  = (float*)alloc((size_t)DIM*DIM*4);
  float* lm2t  = (float*)alloc((size_t)DIM*DIM*4);
  float* lm3t  = (float*)alloc((size_t)DIM*DIM*4);
  float* cm1t  = (float*)alloc((size_t)DIM*DIM*4);
  float* cm2t  = (float*)alloc((size_t)DIM*DIM*4);
  float* cm3t  = (float*)alloc((size_t)DIM*DIM*4);
  float* vw1t  = (float*)alloc((size_t)DIM*DIM*4);
  float* vw2t  = (float*)alloc((size_t)DIM*DIM*4);
  float* WqC   = (float*)alloc((size_t)256*NG*4);
  float* WqL   = (float*)alloc((size_t)384*NG*4);
  float* bqC   = (float*)alloc((size_t)NG*4);
  float* bqL   = (float*)alloc((size_t)NG*4);
  // scratch union: build-phase seg buffers alias round-phase buffers
  char* scratch = (char*)alloc((size_t)28*1024*1024);
  int* scnt_c  = (int*)scratch;
  int* slst_c  = (int*)(scratch + (size_t)NC*CSEG*4);
  int* scnt_l  = (int*)(scratch + (size_t)(NC*CSEG + NC*CSEG*CSEGCAP)*4);
  int* slst_l  = (int*)(scratch + (size_t)(NC*CSEG + NC*CSEG*CSEGCAP + NL*LSEG)*4);
  float* ChB   = (float*)(scratch);                                 // 4 MB
  float* Cpre  = (float*)(scratch + (size_t)4*1024*1024);           // 4 MB
  float* Lpre  = (float*)(scratch + (size_t)8*1024*1024);           // 2 MB
  float* Cmsg  = (float*)(scratch + (size_t)10*1024*1024);          // 4 MB
  float* Lmsg  = (float*)(scratch + (size_t)14*1024*1024);          // 2 MB
  (void)ws_size; (void)in_sizes; (void)n_in; (void)out_size;

  // weight prep
  launch_transpose(lmsg_w1, lm1t, DIM, DIM, stream);
  launch_transpose(lmsg_w2, lm2t, DIM, DIM, stream);
  launch_transpose(lmsg_w3, lm3t, DIM, DIM, stream);
  launch_transpose(cmsg_w1, cm1t, DIM, DIM, stream);
  launch_transpose(cmsg_w2, cm2t, DIM, DIM, stream);
  launch_transpose(cmsg_w3, cm3t, DIM, DIM, stream);
  launch_transpose(lvote_w1, vw1t, DIM, DIM, stream);
  launch_transpose(lvote_w2, vw2t, DIM, DIM, stream);
  k_permq<<<(128*NG)/256, 256, 0, stream>>>(c_wih, 128, WqC, 0);
  k_permq<<<(128*NG)/256, 256, 0, stream>>>(c_whh, 128, WqC, 128);
  k_permq<<<(256*NG)/256, 256, 0, stream>>>(l_wih, 256, WqL, 0);
  k_permq<<<(128*NG)/256, 256, 0, stream>>>(l_whh, 128, WqL, 256);
  k_permb<<<NG/256, 256, 0, stream>>>(c_bih, c_bhh, bqC);
  k_permb<<<NG/256, 256, 0, stream>>>(l_bih, l_bhh, bqL);

  // adjacency build (vectorized), then merge to persistent compact lists
  k_build_cseg<<<(NC/4)*CSEG/256, 256, 0, stream>>>(adj, scnt_c, slst_c);
  k_build_lseg<<<NL*LSEG*64/256, 256, 0, stream>>>(adj, scnt_l, slst_l);
  k_merge_c<<<NC/256, 256, 0, stream>>>(scnt_c, slst_c, ccnt, clst);
  k_merge_l<<<NL/256, 256, 0, stream>>>(scnt_l, slst_l, lcnt, llst);
  k_init<<<NC*DIM/256, 256, 0, stream>>>(l_init_w, l_init_b, c_init_w, c_init_b,
                                         LhA, Lc, ChA, Cc);

  float* Lh_cur = LhA; float* Lh_nxt = LhB;
  float* Ch_cur = ChA; float* Ch_nxt = ChB;

  // prologue: Lpre for round 0
  k_mlp3r<8><<<NL/8, 256, 0, stream>>>(Lh_cur, Lpre,
                                       lm1t, lmsg_b1, lm2t, lmsg_b2, lm3t, lmsg_b3);
  for (int r = 0; r < NROUNDS; ++r){
    k_gather<CCAP><<<NC/8, 256, 0, stream>>>(Lpre, ccnt, clst, Cmsg);
    k_lstm<1,64><<<dim3(NC/64, 8), 256, 0, stream>>>(Cmsg, Ch_cur, WqC, bqC, Cc, Ch_nxt);
    k_mlp3r<8><<<NC/8, 256, 0, stream>>>(Ch_nxt, Cpre,
                                         cm1t, cmsg_b1, cm2t, cmsg_b2, cm3t, cmsg_b3);
    k_gather<LCAP><<<NL/8, 256, 0, stream>>>(Cpre, lcnt, llst, Lmsg);
    k_lstm<2,64><<<dim3(NL/64, 8), 256, 0, stream>>>(Lmsg, Lh_cur, WqL, bqL, Lc, Lh_nxt);
    k_mlp3r<8><<<NL/8, 256, 0, stream>>>(Lh_nxt, Lpre,
                                         lm1t, lmsg_b1, lm2t, lmsg_b2, lm3t, lmsg_b3);
    float* t;
    t = Lh_cur; Lh_cur = Lh_nxt; Lh_nxt = t;
    t = Ch_cur; Ch_cur = Ch_nxt; Ch_nxt = t;
  }

  k_vote<<<NL/8, 256, 0, stream>>>(Lh_cur, vote, (float*)d_out,
                                   vw1t, lvote_b1, vw2t, lvote_b2,
                                   lvote_w3, lvote_b3);
  k_mean<<<1, 256, 0, stream>>>(vote, (float*)d_out);
}